// Round 5
// baseline (284.037 us; speedup 1.0000x reference)
//
#include <hip/hip_runtime.h>

// LengthRegulator: expand x (B,T,H) by per-token durations into (B,MAXLEN,H),
// plus sinusoidal positional rows per within-token offset, plus mel lengths.
// B=64, T=160, H=256, MAXLEN=2000 (fixed by the harness's setup_inputs).
//
// R3 findings: total dur is ~210 us fixed harness cost (1.05 GB d_ws poison
// fill ~162 us + d_out poison ~42 us) + ~60 us for our kernels. Mandatory
// write traffic is 262 MB -> ~45 us floor. R4/R5: nontemporal stores (outputs
// are pure streaming, no reuse -> bypass L2 write-allocate) + FPB 16->40.
// R5 fix: __builtin_nontemporal_store needs a NATIVE vector type, not HIP's
// float4 class -> use ext_vector_type(4) float throughout the vector paths.
constexpr int B      = 64;
constexpr int T      = 160;
constexpr int H      = 256;
constexpr int MAXLEN = 2000;
constexpr int FPB    = 40;   // frames per block (4 waves x 10 frames)
constexpr int NTH    = 256;

typedef float v4f __attribute__((ext_vector_type(4)));

// ---- Kernel A: per-batch scan + frame map build (64 blocks) ----
__global__ __launch_bounds__(NTH) void lr_scan_kernel(
    const int* __restrict__ duration,
    int*       __restrict__ map,      // [B][MAXLEN] packed (idx<<4)|pw, -1 invalid
    float*     __restrict__ out)      // for mel_len chunk
{
    __shared__ int s_scan[NTH];

    const int b   = blockIdx.x;
    const int tid = threadIdx.x;

    int d = (tid < T) ? duration[b * T + tid] : 0;
    s_scan[tid] = d;
    __syncthreads();
    #pragma unroll
    for (int off = 1; off < NTH; off <<= 1) {
        int v   = s_scan[tid];
        int add = (tid >= off) ? s_scan[tid - off] : 0;
        __syncthreads();
        s_scan[tid] = v + add;
        __syncthreads();
    }
    const int csum = s_scan[tid];            // inclusive prefix
    const int mel  = s_scan[T - 1];

    int* mrow = map + b * MAXLEN;

    // token tid covers frames [csum-d, csum): scatter packed entries
    if (tid < T && d > 0) {
        const int start = csum - d;
        for (int f = start; f < csum; ++f)
            mrow[f] = (tid << 4) | (f - start);   // dur < 12 -> pw fits 4 bits
    }
    // invalid tail [mel, MAXLEN)
    for (int f = mel + tid; f < MAXLEN; f += NTH)
        mrow[f] = -1;

    if (tid == 0)
        out[(size_t)2 * B * MAXLEN * H + b] = (float)mel;
}

// ---- Kernel B: pure streaming expand (no LDS, no barriers, nt stores) ----
__global__ __launch_bounds__(NTH) void lr_expand_kernel(
    const float* __restrict__ x,
    const float* __restrict__ pos_enc,
    const int*   __restrict__ map,
    float*       __restrict__ out)
{
    const int b    = blockIdx.y;
    const int f0   = blockIdx.x * FPB;
    const int wave = threadIdx.x >> 6;
    const int lane = threadIdx.x & 63;

    const int* __restrict__ mrow = map + b * MAXLEN + f0;

    const v4f* __restrict__ x4 = (const v4f*)x;
    const v4f* __restrict__ p4 = (const v4f*)pos_enc;
    v4f* __restrict__ o4 = (v4f*)out;

    const size_t out_base = (size_t)b * MAXLEN * (H / 4);
    const size_t pos_base = (size_t)B * MAXLEN * (H / 4) + out_base;

    const v4f zero = (v4f)(0.f);

    // wave w handles frames f0 + w + 4*i, i = 0..9; pipeline 2 frames/iter
    #pragma unroll
    for (int i = 0; i < FPB / 4; i += 2) {
        int   m0 = mrow[wave + (i + 0) * 4];
        int   m1 = mrow[wave + (i + 1) * 4];
        v4f xo0 = zero, po0 = zero, xo1 = zero, po1 = zero;
        if (m0 >= 0) {                         // wave-uniform branch
            xo0 = x4[((size_t)b * T + (m0 >> 4)) * (H / 4) + lane];
            po0 = p4[(size_t)(m0 & 15) * (H / 4) + lane];
        }
        if (m1 >= 0) {
            xo1 = x4[((size_t)b * T + (m1 >> 4)) * (H / 4) + lane];
            po1 = p4[(size_t)(m1 & 15) * (H / 4) + lane];
        }
        const size_t r0 = (size_t)(f0 + wave + (i + 0) * 4) * (H / 4) + lane;
        const size_t r1 = (size_t)(f0 + wave + (i + 1) * 4) * (H / 4) + lane;
        __builtin_nontemporal_store(xo0, &o4[out_base + r0]);
        __builtin_nontemporal_store(po0, &o4[pos_base + r0]);
        __builtin_nontemporal_store(xo1, &o4[out_base + r1]);
        __builtin_nontemporal_store(po1, &o4[pos_base + r1]);
    }
}

extern "C" void kernel_launch(void* const* d_in, const int* in_sizes, int n_in,
                              void* d_out, int out_size, void* d_ws, size_t ws_size,
                              hipStream_t stream)
{
    const float* x        = (const float*)d_in[0];
    const float* pos_enc  = (const float*)d_in[1];
    const int*   duration = (const int*)d_in[2];
    float*       out      = (float*)d_out;
    int*         map      = (int*)d_ws;        // 64*2000*4 = 512 KB

    lr_scan_kernel<<<B, NTH, 0, stream>>>(duration, map, out);

    dim3 grid(MAXLEN / FPB, B);
    lr_expand_kernel<<<grid, NTH, 0, stream>>>(x, pos_enc, map, out);
}

// Round 6
// 271.682 us; speedup vs baseline: 1.0455x; 1.0455x over previous
//
#include <hip/hip_runtime.h>

// LengthRegulator: expand x (B,T,H) by per-token durations into (B,MAXLEN,H),
// plus sinusoidal positional rows per within-token offset, plus mel lengths.
// B=64, T=160, H=256, MAXLEN=2000 (fixed by the harness's setup_inputs).
//
// Final structure (R6 = revert of R5): two-kernel split, plain float4 stores.
// History: R1 per-frame binary search 268.7 us; R2 in-block scatter 269.1;
// R3 two-kernel split 270.4; R5 nontemporal stores + FPB=40 REGRESSED to
// 284.0 (nt streams past L2 and loses write coalescing -> reverted).
// Total time is ~210 us fixed harness cost (1.049 GB d_ws poison fill
// ~163 us + 262 MB d_out poison ~42 us) + ~60 us for our kernels vs a
// ~45 us mandatory 262 MB write floor. Three independent kernel structures
// all measured 269-270 us -> at the measurable floor.
constexpr int B      = 64;
constexpr int T      = 160;
constexpr int H      = 256;
constexpr int MAXLEN = 2000;
constexpr int FPB    = 16;   // frames per block in expand kernel (4 waves x 4)
constexpr int NTH    = 256;

// ---- Kernel A: per-batch scan + frame map build (64 blocks) ----
__global__ __launch_bounds__(NTH) void lr_scan_kernel(
    const int* __restrict__ duration,
    int*       __restrict__ map,      // [B][MAXLEN] packed (idx<<4)|pw, -1 invalid
    float*     __restrict__ out)      // for mel_len chunk
{
    __shared__ int s_scan[NTH];

    const int b   = blockIdx.x;
    const int tid = threadIdx.x;

    int d = (tid < T) ? duration[b * T + tid] : 0;
    s_scan[tid] = d;
    __syncthreads();
    #pragma unroll
    for (int off = 1; off < NTH; off <<= 1) {
        int v   = s_scan[tid];
        int add = (tid >= off) ? s_scan[tid - off] : 0;
        __syncthreads();
        s_scan[tid] = v + add;
        __syncthreads();
    }
    const int csum = s_scan[tid];            // inclusive prefix
    const int mel  = s_scan[T - 1];

    int* mrow = map + b * MAXLEN;

    // token tid covers frames [csum-d, csum): scatter packed entries
    if (tid < T && d > 0) {
        const int start = csum - d;
        for (int f = start; f < csum; ++f)
            mrow[f] = (tid << 4) | (f - start);   // dur < 12 -> pw fits 4 bits
    }
    // invalid tail [mel, MAXLEN)
    for (int f = mel + tid; f < MAXLEN; f += NTH)
        mrow[f] = -1;

    if (tid == 0)
        out[(size_t)2 * B * MAXLEN * H + b] = (float)mel;
}

// ---- Kernel B: pure streaming expand (no LDS, no barriers) ----
__global__ __launch_bounds__(NTH) void lr_expand_kernel(
    const float* __restrict__ x,
    const float* __restrict__ pos_enc,
    const int*   __restrict__ map,
    float*       __restrict__ out)
{
    const int b    = blockIdx.y;
    const int f0   = blockIdx.x * FPB;
    const int wave = threadIdx.x >> 6;
    const int lane = threadIdx.x & 63;

    const int* __restrict__ mrow = map + b * MAXLEN + f0;

    const float4* __restrict__ x4 = (const float4*)x;
    const float4* __restrict__ p4 = (const float4*)pos_enc;
    float4* __restrict__ o4 = (float4*)out;

    const size_t out_base = (size_t)b * MAXLEN * (H / 4);
    const size_t pos_base = (size_t)B * MAXLEN * (H / 4) + out_base;

    int m[4];
    #pragma unroll
    for (int i = 0; i < 4; ++i) m[i] = mrow[wave + i * 4];   // wave-uniform

    float4 xo[4], po[4];
    #pragma unroll
    for (int i = 0; i < 4; ++i) {
        xo[i] = make_float4(0.f, 0.f, 0.f, 0.f);
        po[i] = xo[i];
        if (m[i] >= 0) {                       // wave-uniform branch
            const int idx = m[i] >> 4;
            const int pw  = m[i] & 15;
            xo[i] = x4[((size_t)b * T + idx) * (H / 4) + lane];
            po[i] = p4[(size_t)pw * (H / 4) + lane];
        }
    }
    #pragma unroll
    for (int i = 0; i < 4; ++i) {
        const int f = f0 + wave + i * 4;       // 4 waves cover 4 adjacent rows
        o4[out_base + (size_t)f * (H / 4) + lane] = xo[i];
        o4[pos_base + (size_t)f * (H / 4) + lane] = po[i];
    }
}

extern "C" void kernel_launch(void* const* d_in, const int* in_sizes, int n_in,
                              void* d_out, int out_size, void* d_ws, size_t ws_size,
                              hipStream_t stream)
{
    const float* x        = (const float*)d_in[0];
    const float* pos_enc  = (const float*)d_in[1];
    const int*   duration = (const int*)d_in[2];
    float*       out      = (float*)d_out;
    int*         map      = (int*)d_ws;        // 64*2000*4 = 512 KB

    lr_scan_kernel<<<B, NTH, 0, stream>>>(duration, map, out);

    dim3 grid(MAXLEN / FPB, B);
    lr_expand_kernel<<<grid, NTH, 0, stream>>>(x, pos_enc, map, out);
}